// Round 2
// baseline (2776.701 us; speedup 1.0000x reference)
//
#include <hip/hip_runtime.h>

#define WB 4
#define WN 4096
#define WKNN 20
#define WM 1024
#define WOUTK 8
#define WOD 256
#define BEPS 1e-5f

typedef unsigned long long u64;
typedef unsigned int u32;

// ---- workspace element offsets (floats/ints, 4B units) ----
#define ACC_F    0        // 1280 floats of stat accumulators (memset to 0 each launch)
#define IDX1_I   2048     // [B][N][20] knn-1 indices
#define IDX2NN_I 329728   // [B][N][20] knn-2 indices
#define IDX2_I   657408   // [B][1024] fps indices
#define X1_F     661504   // [B][N][64]
#define XX1_F    1710080  // [B][N]
#define X2_F     1726464  // [B][N][64]
// total ws use: 2775040 floats = ~11.1 MB

// ---- output element offsets ----
#define O_F   0
#define O_C   1048576
#define O_P2A 2097152
#define O_P2B 2109440
#define O_M0  2121728
#define O_M1  2125824

__device__ __forceinline__ u64 shflx64(u64 v, int m){
    int lo = __shfl_xor((int)(u32)(v & 0xFFFFFFFFull), m, 64);
    int hi = __shfl_xor((int)(u32)(v >> 32), m, 64);
    return ((u64)(u32)hi << 32) | (u32)lo;
}
// monotone float->u32 map (total order incl. negatives)
__device__ __forceinline__ u32 encf(float d){
    u32 u = __float_as_uint(d);
    return (u & 0x80000000u) ? ~u : (u | 0x80000000u);
}
// sorted-ascending insert into register list (fast-path guarded)
template<int L>
__device__ __forceinline__ void ins(u64* lst, u64 key){
    if (key < lst[L-1]){
        #pragma unroll
        for (int j = 0; j < L; ++j){
            u64 a = lst[j];
            u64 mn = key < a ? key : a;
            u64 mx = key < a ? a : key;
            lst[j] = mn; key = mx;
        }
    }
}

// ============================================================
// K1: blocks 0..3 -> FPS per batch (also writes p2 x2, masks x2)
//     blocks 4..1027 -> knn-1 (16 queries per block, wave/query)
// ============================================================
__global__ __launch_bounds__(1024,1)
void k1_fps_knn1(const float* __restrict__ x, float* __restrict__ out,
                 int* __restrict__ idx1, int* __restrict__ idx2){
    __shared__ float px[WN], py[WN], pz[WN];
    __shared__ u64 warr[2][16];
    int tid = threadIdx.x;
    bool isf = (blockIdx.x < 4);
    int b = isf ? (int)blockIdx.x : (int)((blockIdx.x - 4) >> 8);
    const float* xb = x + b*WN*3;
    for (int i = tid; i < WN*3; i += 1024){
        float v = xb[i];
        int n = i/3, c = i - n*3;
        if (c==0) px[n]=v; else if (c==1) py[n]=v; else pz[n]=v;
    }
    __syncthreads();
    if (isf){
        // masks (all ones, both copies)
        for (int i = tid; i < WM; i += 1024){
            out[O_M0 + b*WM + i] = 1.0f;
            out[O_M1 + b*WM + i] = 1.0f;
        }
        float ptx[4],pty[4],ptz[4],dst[4];
        #pragma unroll
        for (int j=0;j<4;++j){
            int p = tid + j*1024;
            ptx[j]=px[p]; pty[j]=py[p]; ptz[j]=pz[p];
            dst[j]=1e10f;
        }
        if (tid==0){
            idx2[b*WM] = 0;
            int o3 = (b*WM)*3;
            out[O_P2A+o3]=px[0]; out[O_P2A+o3+1]=py[0]; out[O_P2A+o3+2]=pz[0];
            out[O_P2B+o3]=px[0]; out[O_P2B+o3+1]=py[0]; out[O_P2B+o3+2]=pz[0];
        }
        int last = 0;
        for (int it=1; it<WM; ++it){
            float lx=px[last], ly=py[last], lz=pz[last];
            u64 bk=0;
            #pragma unroll
            for (int j=0;j<4;++j){
                float dx=ptx[j]-lx, dy=pty[j]-ly, dz=ptz[j]-lz;
                float d = dx*dx + dy*dy + dz*dz;
                dst[j] = fminf(dst[j], d);
                // argmax key: larger dist wins, tie -> smaller index
                u64 k = ((u64)__float_as_uint(dst[j])<<32) | (u32)(4095 - (tid + j*1024));
                bk = k > bk ? k : bk;
            }
            #pragma unroll
            for (int m=32;m;m>>=1){ u64 o = shflx64(bk,m); bk = o>bk?o:bk; }
            if ((tid&63)==0) warr[it&1][tid>>6] = bk;
            __syncthreads();
            u64 best = warr[it&1][0];
            #pragma unroll
            for (int w=1;w<16;++w){ u64 o = warr[it&1][w]; best = o>best?o:best; }
            last = 4095 - (int)(best & 0xFFFFFFFFu);
            if (tid==0){
                idx2[b*WM+it] = last;
                float vx=px[last], vy=py[last], vz=pz[last];
                int o3 = (b*WM+it)*3;
                out[O_P2A+o3]=vx; out[O_P2A+o3+1]=vy; out[O_P2A+o3+2]=vz;
                out[O_P2B+o3]=vx; out[O_P2B+o3+1]=vy; out[O_P2B+o3+2]=vz;
            }
        }
    } else {
        int wid = tid>>6, lane = tid&63;
        int grow = ((int)blockIdx.x-4)*16 + wid;   // global row, same batch across block
        int n = grow & 4095;
        float qx=px[n], qy=py[n], qz=pz[n];
        float qq = qx*qx+qy*qy+qz*qz;
        u64 lst[WKNN];
        #pragma unroll
        for (int j=0;j<WKNN;++j) lst[j]=~0ull;
        for (int t=0;t<64;++t){
            int c = lane + t*64;
            float sx=px[c], sy=py[c], sz=pz[c];
            float ss = sx*sx+sy*sy+sz*sz;
            float inner = qx*sx+qy*sy+qz*sz;
            float nd = (2.0f*inner - qq) - ss;   // reference formula order
            // maximize nd, tie -> smaller index  => ascending key
            u64 key = ((u64)(0xFFFFFFFFu - encf(nd))<<32) | (u32)c;
            ins<WKNN>(lst, key);
        }
        int ob = grow*WKNN;
        for (int r=0;r<WKNN;++r){
            u64 k = lst[0];
            #pragma unroll
            for (int m=32;m;m>>=1){ u64 o = shflx64(k,m); k = o<k?o:k; }
            if (lane==0) idx1[ob+r] = (int)(k & 0xFFFFFFFFu);
            if (lst[0]==k){
                #pragma unroll
                for (int j=0;j<WKNN-1;++j) lst[j]=lst[j+1];
                lst[WKNN-1]=~0ull;
            }
        }
    }
}

// ============================================================
// K2: edgeconv1 BN stats (sum, sumsq per 64 ch over B*N*K)
// ============================================================
__global__ __launch_bounds__(256,1)
void k2_ec1_stats(const float* __restrict__ x, const float* __restrict__ w1,
                  const int* __restrict__ idx1, float* __restrict__ acc){
    __shared__ float as[64], aq[64];
    int tid = threadIdx.x;
    if (tid < 64){ as[tid]=0.f; aq[tid]=0.f; }
    __syncthreads();
    int cg = tid & 7, sg = tid >> 3;
    int chb = cg*8;
    float w[8][6];
    #pragma unroll
    for (int i=0;i<8;++i){
        #pragma unroll
        for (int j=0;j<6;++j) w[i][j] = w1[(chb+i)*6+j];
    }
    float s[8]={0,0,0,0,0,0,0,0}, q[8]={0,0,0,0,0,0,0,0};
    int s0 = (int)blockIdx.x*1024 + sg*32;
    for (int i=0;i<32;++i){
        int smp = s0+i;
        int bn = smp/WKNN;
        int j = idx1[smp];
        int bb = bn >> 12;
        const float* ct = x + bn*3;
        const float* nb = x + (bb*WN + j)*3;
        float c0=ct[0],c1=ct[1],c2=ct[2];
        float f0=nb[0]-c0, f1=nb[1]-c1, f2=nb[2]-c2;
        #pragma unroll
        for (int c=0;c<8;++c){
            float y = w[c][0]*f0 + w[c][1]*f1 + w[c][2]*f2
                    + w[c][3]*c0 + w[c][4]*c1 + w[c][5]*c2;
            s[c] += y; q[c] = fmaf(y,y,q[c]);
        }
    }
    #pragma unroll
    for (int c=0;c<8;++c){ atomicAdd(&as[chb+c], s[c]); atomicAdd(&aq[chb+c], q[c]); }
    __syncthreads();
    if (tid < 64){ atomicAdd(&acc[tid], as[tid]); atomicAdd(&acc[64+tid], aq[tid]); }
}

// ============================================================
// K4: edgeconv1 apply (BN + leaky + max over k) -> x1 [B,N,64]
// ============================================================
__global__ __launch_bounds__(256,1)
void k4_ec1_apply(const float* __restrict__ x, const float* __restrict__ w1,
                  const float* __restrict__ g1, const float* __restrict__ b1,
                  const int* __restrict__ idx1, const float* __restrict__ acc,
                  float* __restrict__ x1){
    int lin = (int)blockIdx.x*256 + threadIdx.x;
    int row = lin >> 3, cg = lin & 7, chb = cg*8;
    int bb = row >> 12;
    const float Pinv = 1.0f/(float)(WB*WN*WKNN);
    float aa[8], cc[8], w[8][6];
    #pragma unroll
    for (int i=0;i<8;++i){
        int ch = chb+i;
        float mean = acc[ch]*Pinv;
        float var  = acc[64+ch]*Pinv - mean*mean;
        float rstd = rsqrtf(var + BEPS);
        aa[i] = g1[ch]*rstd;
        cc[i] = b1[ch] - mean*aa[i];
        #pragma unroll
        for (int j=0;j<6;++j) w[i][j]=w1[ch*6+j];
    }
    const float* ct = x + row*3;
    float c0=ct[0],c1=ct[1],c2=ct[2];
    float mx[8];
    #pragma unroll
    for (int i=0;i<8;++i) mx[i] = -1e30f;
    for (int k=0;k<WKNN;++k){
        int j = idx1[row*WKNN+k];
        const float* nb = x + (bb*WN + j)*3;
        float f0=nb[0]-c0, f1=nb[1]-c1, f2=nb[2]-c2;
        #pragma unroll
        for (int c=0;c<8;++c){
            float y = w[c][0]*f0 + w[c][1]*f1 + w[c][2]*f2
                    + w[c][3]*c0 + w[c][4]*c1 + w[c][5]*c2;
            float v = fmaf(y, aa[c], cc[c]);
            v = fmaxf(v, 0.2f*v);
            mx[c] = fmaxf(mx[c], v);
        }
    }
    #pragma unroll
    for (int c=0;c<8;++c) x1[row*64 + chb + c] = mx[c];
}

// ============================================================
// K5: xx1[row] = sum(x1[row]^2)
// ============================================================
__global__ __launch_bounds__(256,1)
void k5_xx1(const float* __restrict__ x1, float* __restrict__ xx1){
    int wid = threadIdx.x>>6, lane = threadIdx.x&63;
    int row = (int)blockIdx.x*4 + wid;
    float v = x1[row*64+lane];
    float s = v*v;
    #pragma unroll
    for (int m=32;m;m>>=1) s += __shfl_xor(s,m,64);
    if (lane==0) xx1[row]=s;
}

// ============================================================
// K6: knn-2 on x1 (C=64): fused 64x128x64 reg-tiled GEMM + top-20
// grid 256 (B x 64 q-tiles), 512 threads
// ============================================================
__global__ __launch_bounds__(512,1)
void k6_knn2(const float* __restrict__ x1, const float* __restrict__ xx1,
             int* __restrict__ idx2nn){
    __shared__ __align__(16) float Qt[64*64];
    __shared__ __align__(16) float St[128*68];
    __shared__ float Sxx[128];
    float* Dt = St;  // dist tile [64][132] overlays St (8448 <= 8704 floats)
    int tid = threadIdx.x, wid = tid>>6, lane = tid&63;
    int b = (int)blockIdx.x >> 6, qt = (int)blockIdx.x & 63;
    const float* xb = x1 + b*WN*64;
    for (int i=tid; i<64*16; i+=512){
        int r = i>>4, c4 = i&15;
        *(float4*)&Qt[r*64 + c4*4] = *(const float4*)&xb[(qt*64+r)*64 + c4*4];
    }
    float qxx[8];
    #pragma unroll
    for (int i=0;i<8;++i) qxx[i] = xx1[b*WN + qt*64 + wid*8 + i];
    u64 lst[WKNN];
    #pragma unroll
    for (int j=0;j<WKNN;++j) lst[j]=~0ull;
    int sq = tid>>3, seg = tid&7;
    for (int ct=0; ct<32; ++ct){
        int cb = ct*128;
        __syncthreads();   // protect St/Dt from previous iteration readers
        for (int i=tid; i<128*16; i+=512){
            int r=i>>4, c4=i&15;
            *(float4*)&St[r*68 + c4*4] = *(const float4*)&xb[(cb+r)*64 + c4*4];
        }
        if (tid < 128) Sxx[tid] = xx1[b*WN + cb + tid];
        __syncthreads();
        float acc[8][2];
        #pragma unroll
        for (int i=0;i<8;++i){ acc[i][0]=0.f; acc[i][1]=0.f; }
        #pragma unroll 4
        for (int d4=0; d4<16; ++d4){
            float4 s0 = *(const float4*)&St[lane*68 + d4*4];
            float4 s1 = *(const float4*)&St[(lane+64)*68 + d4*4];
            #pragma unroll
            for (int i=0;i<8;++i){
                float4 qv = *(const float4*)&Qt[(wid*8+i)*64 + d4*4];
                acc[i][0] += qv.x*s0.x + qv.y*s0.y + qv.z*s0.z + qv.w*s0.w;
                acc[i][1] += qv.x*s1.x + qv.y*s1.y + qv.z*s1.z + qv.w*s1.w;
            }
        }
        __syncthreads();   // all waves done reading St before Dt overwrite
        float sx0 = Sxx[lane], sx1 = Sxx[lane+64];
        #pragma unroll
        for (int i=0;i<8;++i){
            int r = wid*8+i;
            Dt[r*132 + lane]      = (2.0f*acc[i][0] - qxx[i]) - sx0;
            Dt[r*132 + lane + 64] = (2.0f*acc[i][1] - qxx[i]) - sx1;
        }
        __syncthreads();
        #pragma unroll
        for (int m=0;m<16;++m){
            int col = seg*16+m;
            float nd = Dt[sq*132 + col];
            u64 key = ((u64)(0xFFFFFFFFu - encf(nd))<<32) | (u32)(cb+col);
            ins<WKNN>(lst,key);
        }
    }
    // merge 8 seg-threads (consecutive, same wave) per query
    int ob = (b*WN + qt*64 + sq)*WKNN;
    for (int r=0;r<WKNN;++r){
        u64 k = lst[0];
        #pragma unroll
        for (int m=4;m;m>>=1){ u64 o=shflx64(k,m); k = o<k?o:k; }
        if ((tid&7)==0) idx2nn[ob+r] = (int)(k & 0xFFFFFFFFu);
        if (lst[0]==k){
            #pragma unroll
            for (int j=0;j<WKNN-1;++j) lst[j]=lst[j+1];
            lst[WKNN-1]=~0ull;
        }
    }
}

// ============================================================
// K7: edgeconv2 BN stats. grid 256 x 512 thr; wave=8ch, lane=row
// ============================================================
__global__ __launch_bounds__(512,1)
void k7_ec2_stats(const float* __restrict__ x1, const float* __restrict__ w2,
                  const int* __restrict__ idx2nn, float* __restrict__ acc){
    __shared__ __align__(16) float wsm[64*128];
    __shared__ float as[64], aq[64];
    int tid = threadIdx.x, wid = tid>>6, lane = tid&63;
    for (int i=tid; i<2048; i+=512)
        *(float4*)&wsm[i*4] = *(const float4*)&w2[i*4];
    if (tid<64){ as[tid]=0.f; aq[tid]=0.f; }
    __syncthreads();
    int row = (int)blockIdx.x*64 + lane;
    int b = row >> 12;
    const float* xr  = x1 + row*64;
    const float* xbb = x1 + b*WN*64;
    float ss[8]={0,0,0,0,0,0,0,0}, qs[8]={0,0,0,0,0,0,0,0};
    for (int kc=0; kc<5; ++kc){
        int jj[4];
        #pragma unroll
        for (int kk=0;kk<4;++kk) jj[kk] = idx2nn[row*WKNN + kc*4 + kk];
        float av[8][4];
        #pragma unroll
        for (int c=0;c<8;++c){ av[c][0]=0;av[c][1]=0;av[c][2]=0;av[c][3]=0; }
        #pragma unroll 4
        for (int dc=0; dc<16; ++dc){
            float4 cv = *(const float4*)&xr[dc*4];
            float4 fv[4];
            #pragma unroll
            for (int kk=0;kk<4;++kk){
                float4 nv = *(const float4*)&xbb[jj[kk]*64 + dc*4];
                fv[kk].x=nv.x-cv.x; fv[kk].y=nv.y-cv.y; fv[kk].z=nv.z-cv.z; fv[kk].w=nv.w-cv.w;
            }
            #pragma unroll
            for (int c=0;c<8;++c){
                float4 wv = *(const float4*)&wsm[(wid*8+c)*128 + dc*4];
                #pragma unroll
                for (int kk=0;kk<4;++kk)
                    av[c][kk] += wv.x*fv[kk].x + wv.y*fv[kk].y + wv.z*fv[kk].z + wv.w*fv[kk].w;
            }
        }
        #pragma unroll 4
        for (int dc=16; dc<32; ++dc){
            float4 cv = *(const float4*)&xr[(dc-16)*4];
            #pragma unroll
            for (int c=0;c<8;++c){
                float4 wv = *(const float4*)&wsm[(wid*8+c)*128 + dc*4];
                float dv = wv.x*cv.x + wv.y*cv.y + wv.z*cv.z + wv.w*cv.w;
                #pragma unroll
                for (int kk=0;kk<4;++kk) av[c][kk] += dv;
            }
        }
        #pragma unroll
        for (int c=0;c<8;++c){
            #pragma unroll
            for (int kk=0;kk<4;++kk){ ss[c]+=av[c][kk]; qs[c]=fmaf(av[c][kk],av[c][kk],qs[c]); }
        }
    }
    #pragma unroll
    for (int c=0;c<8;++c){ atomicAdd(&as[wid*8+c], ss[c]); atomicAdd(&aq[wid*8+c], qs[c]); }
    __syncthreads();
    if (tid<64){ atomicAdd(&acc[128+tid], as[tid]); atomicAdd(&acc[192+tid], aq[tid]); }
}

// ============================================================
// K9: edgeconv2 apply -> x2 [B,N,64]
// ============================================================
__global__ __launch_bounds__(512,1)
void k9_ec2_apply(const float* __restrict__ x1, const float* __restrict__ w2,
                  const float* __restrict__ g2, const float* __restrict__ b2,
                  const int* __restrict__ idx2nn, const float* __restrict__ acc,
                  float* __restrict__ x2){
    __shared__ __align__(16) float wsm[64*128];
    int tid = threadIdx.x, wid = tid>>6, lane = tid&63;
    for (int i=tid; i<2048; i+=512)
        *(float4*)&wsm[i*4] = *(const float4*)&w2[i*4];
    __syncthreads();
    const float Pinv = 1.0f/(float)(WB*WN*WKNN);
    float aa[8], cc[8];
    #pragma unroll
    for (int c=0;c<8;++c){
        int ch = wid*8+c;
        float mean = acc[128+ch]*Pinv;
        float var  = acc[192+ch]*Pinv - mean*mean;
        float rstd = rsqrtf(var + BEPS);
        aa[c] = g2[ch]*rstd;
        cc[c] = b2[ch] - mean*aa[c];
    }
    int row = (int)blockIdx.x*64 + lane;
    int b = row>>12;
    const float* xr  = x1 + row*64;
    const float* xbb = x1 + b*WN*64;
    float mx[8];
    #pragma unroll
    for (int c=0;c<8;++c) mx[c] = -1e30f;
    for (int kc=0;kc<5;++kc){
        int jj[4];
        #pragma unroll
        for (int kk=0;kk<4;++kk) jj[kk]=idx2nn[row*WKNN+kc*4+kk];
        float av[8][4];
        #pragma unroll
        for (int c=0;c<8;++c){ av[c][0]=0;av[c][1]=0;av[c][2]=0;av[c][3]=0; }
        #pragma unroll 4
        for (int dc=0;dc<16;++dc){
            float4 cv = *(const float4*)&xr[dc*4];
            float4 fv[4];
            #pragma unroll
            for (int kk=0;kk<4;++kk){
                float4 nv = *(const float4*)&xbb[jj[kk]*64 + dc*4];
                fv[kk].x=nv.x-cv.x; fv[kk].y=nv.y-cv.y; fv[kk].z=nv.z-cv.z; fv[kk].w=nv.w-cv.w;
            }
            #pragma unroll
            for (int c=0;c<8;++c){
                float4 wv = *(const float4*)&wsm[(wid*8+c)*128 + dc*4];
                #pragma unroll
                for (int kk=0;kk<4;++kk)
                    av[c][kk] += wv.x*fv[kk].x + wv.y*fv[kk].y + wv.z*fv[kk].z + wv.w*fv[kk].w;
            }
        }
        #pragma unroll 4
        for (int dc=16;dc<32;++dc){
            float4 cv = *(const float4*)&xr[(dc-16)*4];
            #pragma unroll
            for (int c=0;c<8;++c){
                float4 wv = *(const float4*)&wsm[(wid*8+c)*128 + dc*4];
                float dv = wv.x*cv.x + wv.y*cv.y + wv.z*cv.z + wv.w*cv.w;
                #pragma unroll
                for (int kk=0;kk<4;++kk) av[c][kk] += dv;
            }
        }
        #pragma unroll
        for (int c=0;c<8;++c){
            #pragma unroll
            for (int kk=0;kk<4;++kk){
                float v = fmaf(av[c][kk], aa[c], cc[c]);
                v = fmaxf(v, 0.2f*v);
                mx[c] = fmaxf(mx[c], v);
            }
        }
    }
    #pragma unroll
    for (int c=0;c<8;++c) x2[row*64 + wid*8 + c] = mx[c];
}

// ============================================================
// K10: out-knn (top-8 of p2 vs x), agg = mean of x2 rows,
//      pre-BN Yf/Yc written TRANSPOSED directly into out,
//      accumulate BN stats.
// grid 256 (16 queries each), 256 thr (wave/query x4 sequential)
// ============================================================
__global__ __launch_bounds__(256,1)
void k10_out(const float* __restrict__ x, const float* __restrict__ x2,
             const int* __restrict__ idx2, const float* __restrict__ wf,
             const float* __restrict__ wc, float* __restrict__ out,
             float* __restrict__ acc){
    __shared__ float px[WN], py[WN], pz[WN];
    __shared__ __align__(16) float aggs[4][64];
    __shared__ float sacc[1024];
    int tid=threadIdx.x, wid=tid>>6, lane=tid&63;
    int b = (int)blockIdx.x >> 6;
    int mb = ((int)blockIdx.x & 63)*16;
    const float* xb = x + b*WN*3;
    for (int i=tid;i<WN*3;i+=256){
        float v=xb[i]; int n=i/3,c=i-n*3;
        if(c==0)px[n]=v; else if(c==1)py[n]=v; else pz[n]=v;
    }
    for (int i=tid;i<1024;i+=256) sacc[i]=0.f;
    __syncthreads();
    for (int qq=0;qq<4;++qq){
        int m = mb + wid*4 + qq;
        int pi = idx2[b*WM+m];
        float qx=px[pi], qy=py[pi], qz=pz[pi];
        u64 lst[WOUTK];
        #pragma unroll
        for (int j=0;j<WOUTK;++j) lst[j]=~0ull;
        for (int t=0;t<64;++t){
            int c = lane + t*64;
            float dx=qx-px[c], dy=qy-py[c], dz=qz-pz[c];
            float d = dx*dx+dy*dy+dz*dz;
            u64 key = ((u64)encf(d)<<32) | (u32)c;   // min d, tie -> min idx
            ins<WOUTK>(lst,key);
        }
        int jr[WOUTK];
        #pragma unroll
        for (int r=0;r<WOUTK;++r){
            u64 k=lst[0];
            #pragma unroll
            for (int mm=32;mm;mm>>=1){ u64 o=shflx64(k,mm); k = o<k?o:k; }
            jr[r] = (int)(k&0xFFFFFFFFu);
            if (lst[0]==k){
                #pragma unroll
                for (int j=0;j<WOUTK-1;++j) lst[j]=lst[j+1];
                lst[WOUTK-1]=~0ull;
            }
        }
        float a = 0.f;
        #pragma unroll
        for (int r=0;r<WOUTK;++r) a += x2[(b*WN + jr[r])*64 + lane];
        a *= 0.125f;
        aggs[wid][lane] = a;
        __syncthreads();
        #pragma unroll
        for (int i=0;i<4;++i){
            int o = lane + 64*i;
            const float4* wfp = (const float4*)(wf + o*64);
            const float4* wcp = (const float4*)(wc + o*64);
            float af=0.f, ac=0.f;
            #pragma unroll
            for (int d4=0;d4<16;++d4){
                float4 avv = *(const float4*)&aggs[wid][d4*4];
                float4 w1v = wfp[d4];
                float4 w2v = wcp[d4];
                af += w1v.x*avv.x + w1v.y*avv.y + w1v.z*avv.z + w1v.w*avv.w;
                ac += w2v.x*avv.x + w2v.y*avv.y + w2v.z*avv.z + w2v.w*avv.w;
            }
            // pre-BN values straight to final transposed slot [b, o, m]
            out[O_F + (b*WOD + o)*WM + m] = af;
            out[O_C + (b*WOD + o)*WM + m] = ac;
            atomicAdd(&sacc[o],       af);
            atomicAdd(&sacc[256+o],   af*af);
            atomicAdd(&sacc[512+o],   ac);
            atomicAdd(&sacc[768+o],   ac*ac);
        }
        __syncthreads();
    }
    for (int i=tid;i<1024;i+=256) atomicAdd(&acc[256+i], sacc[i]);
}

// ============================================================
// K12: in-place BN-normalize the f/c halves of out (coalesced)
// ============================================================
__global__ __launch_bounds__(256,1)
void k12_final(const float* __restrict__ acc,
               const float* __restrict__ gf, const float* __restrict__ bf,
               const float* __restrict__ gc, const float* __restrict__ bc,
               float* __restrict__ out){
    int t = (int)blockIdx.x*256 + threadIdx.x;   // 0 .. 2*2^20
    int half = t >> 20;
    int r = t & 0xFFFFF;
    int o = (r >> 10) & 255;
    const float Pinv = 1.0f/4096.0f;
    float sum = acc[(half?768:256) + o];
    float sq  = acc[(half?1024:512) + o];
    float mean = sum*Pinv;
    float var  = sq*Pinv - mean*mean;
    float rstd = rsqrtf(var + BEPS);
    float g  = half ? gc[o] : gf[o];
    float bb = half ? bc[o] : bf[o];
    float y = out[t];
    out[t] = (y-mean)*rstd*g + bb;
}

extern "C" void kernel_launch(void* const* d_in, const int* in_sizes, int n_in,
                              void* d_out, int out_size, void* d_ws, size_t ws_size,
                              hipStream_t stream){
    const float* x  = (const float*)d_in[0];
    const float* w1 = (const float*)d_in[1];
    const float* g1 = (const float*)d_in[2];
    const float* b1 = (const float*)d_in[3];
    const float* w2 = (const float*)d_in[4];
    const float* g2 = (const float*)d_in[5];
    const float* b2 = (const float*)d_in[6];
    const float* wf = (const float*)d_in[7];
    const float* gf = (const float*)d_in[8];
    const float* bf = (const float*)d_in[9];
    const float* wc = (const float*)d_in[10];
    const float* gc = (const float*)d_in[11];
    const float* bc = (const float*)d_in[12];
    float* out = (float*)d_out;
    float* wsf = (float*)d_ws;
    int*   wsi = (int*)d_ws;
    float* ACC    = wsf + ACC_F;
    int*   idx1   = wsi + IDX1_I;
    int*   idx2nn = wsi + IDX2NN_I;
    int*   idx2   = wsi + IDX2_I;
    float* x1     = wsf + X1_F;
    float* xx1    = wsf + XX1_F;
    float* x2     = wsf + X2_F;

    hipMemsetAsync(ACC, 0, 1280*sizeof(float), stream);
    k1_fps_knn1 <<<1028,1024,0,stream>>>(x,out,idx1,idx2);
    k2_ec1_stats<<<320, 256, 0,stream>>>(x,w1,idx1,ACC);
    k4_ec1_apply<<<512, 256, 0,stream>>>(x,w1,g1,b1,idx1,ACC,x1);
    k5_xx1      <<<4096,256, 0,stream>>>(x1,xx1);
    k6_knn2     <<<256, 512, 0,stream>>>(x1,xx1,idx2nn);
    k7_ec2_stats<<<256, 512, 0,stream>>>(x1,w2,idx2nn,ACC);
    k9_ec2_apply<<<256, 512, 0,stream>>>(x1,w2,g2,b2,idx2nn,ACC,x2);
    k10_out     <<<256, 256, 0,stream>>>(x,x2,idx2,wf,wc,out,ACC);
    k12_final   <<<8192,256, 0,stream>>>(ACC,gf,bf,gc,bc,out);
}

// Round 3
// 1928.165 us; speedup vs baseline: 1.4401x; 1.4401x over previous
//
#include <hip/hip_runtime.h>

#define WB 4
#define WN 4096
#define WKNN 20
#define WM 1024
#define WOUTK 8
#define WOD 256
#define BEPS 1e-5f

typedef unsigned long long u64;
typedef unsigned int u32;

// ---- workspace element offsets (floats/ints, 4B units) ----
#define ACC_F    0        // 1280 floats of stat accumulators (memset to 0 each launch)
#define IDX1_I   2048     // [B][N][20] knn-1 indices
#define IDX2NN_I 329728   // [B][N][20] knn-2 indices
#define IDX2_I   657408   // [B][1024] fps indices
#define X1_F     661504   // [B][N][64]
#define XX1_F    1710080  // [B][N]
#define X2_F     1726464  // [B][N][64]
// total ws use: 2775040 floats = ~11.1 MB

// ---- output element offsets ----
#define O_F   0
#define O_C   1048576
#define O_P2A 2097152
#define O_P2B 2109440
#define O_M0  2121728
#define O_M1  2125824

__device__ __forceinline__ u64 shflx64(u64 v, int m){
    int lo = __shfl_xor((int)(u32)(v & 0xFFFFFFFFull), m, 64);
    int hi = __shfl_xor((int)(u32)(v >> 32), m, 64);
    return ((u64)(u32)hi << 32) | (u32)lo;
}
// monotone float->u32 map (total order incl. negatives)
__device__ __forceinline__ u32 encf(float d){
    u32 u = __float_as_uint(d);
    return (u & 0x80000000u) ? ~u : (u | 0x80000000u);
}
// sorted-ascending insert into register list (fast-path guarded)
template<int L>
__device__ __forceinline__ void ins(u64* lst, u64 key){
    if (key < lst[L-1]){
        #pragma unroll
        for (int j = 0; j < L; ++j){
            u64 a = lst[j];
            u64 mn = key < a ? key : a;
            u64 mx = key < a ? a : key;
            lst[j] = mn; key = mx;
        }
    }
}

// DPP-based 64-bit max step: keys are (distbits<<32)|tiebreak with distbits
// = positive-f32 bits < 0x7f800000, so the f64 bit pattern is a positive
// finite double and v_max_f64 == u64 max. old value fills masked/invalid
// lanes (fmax with self = no-op).
template<int CTRL, int RM>
__device__ __forceinline__ double dppmax64(double v){
    int lo = __double2loint(v), hi = __double2hiint(v);
    int slo = __builtin_amdgcn_update_dpp(lo, lo, CTRL, RM, 0xF, false);
    int shi = __builtin_amdgcn_update_dpp(hi, hi, CTRL, RM, 0xF, false);
    return fmax(v, __hiloint2double(shi, slo));
}
// full wave64 max -> lane 63 (row_shr 1,2,4,8; bcast15 rows 1,3; bcast31 rows 2,3)
__device__ __forceinline__ double wavemax64(double v){
    v = dppmax64<0x111,0xF>(v);
    v = dppmax64<0x112,0xF>(v);
    v = dppmax64<0x114,0xF>(v);
    v = dppmax64<0x118,0xF>(v);
    v = dppmax64<0x142,0xA>(v);
    v = dppmax64<0x143,0xC>(v);
    return v;
}
// max over 16 values replicated in each 16-lane row -> all lanes
__device__ __forceinline__ double rowmax16(double v){
    v = dppmax64<0x128,0xF>(v);   // row_ror:8
    v = dppmax64<0x124,0xF>(v);   // row_ror:4
    v = dppmax64<0x4E,0xF>(v);    // quad_perm xor2
    v = dppmax64<0xB1,0xF>(v);    // quad_perm xor1
    return v;
}

// ============================================================
// K1: blocks 0..3 -> FPS per batch (also writes p2 x2, masks x2)
//     blocks 4..1027 -> knn-1 (16 queries per block, wave/query)
// ============================================================
__global__ __launch_bounds__(1024,1)
void k1_fps_knn1(const float* __restrict__ x, float* __restrict__ out,
                 int* __restrict__ idx1, int* __restrict__ idx2){
    __shared__ float px[WN], py[WN], pz[WN];
    __shared__ double warr[2][16];
    int tid = threadIdx.x;
    bool isf = (blockIdx.x < 4);
    int b = isf ? (int)blockIdx.x : (int)((blockIdx.x - 4) >> 8);
    const float* xb = x + b*WN*3;
    for (int i = tid; i < WN*3; i += 1024){
        float v = xb[i];
        int n = i/3, c = i - n*3;
        if (c==0) px[n]=v; else if (c==1) py[n]=v; else pz[n]=v;
    }
    __syncthreads();
    if (isf){
        // masks (all ones, both copies)
        for (int i = tid; i < WM; i += 1024){
            out[O_M0 + b*WM + i] = 1.0f;
            out[O_M1 + b*WM + i] = 1.0f;
        }
        float ptx[4],pty[4],ptz[4],dst[4];
        #pragma unroll
        for (int j=0;j<4;++j){
            int p = tid + j*1024;
            ptx[j]=px[p]; pty[j]=py[p]; ptz[j]=pz[p];
            dst[j]=1e10f;
        }
        if (tid==0){
            idx2[b*WM] = 0;
            int o3 = (b*WM)*3;
            out[O_P2A+o3]=px[0]; out[O_P2A+o3+1]=py[0]; out[O_P2A+o3+2]=pz[0];
            out[O_P2B+o3]=px[0]; out[O_P2B+o3+1]=py[0]; out[O_P2B+o3+2]=pz[0];
        }
        float lx=px[0], ly=py[0], lz=pz[0];
        for (int it=1; it<WM; ++it){
            // A: update dists, pack (dist, tiebreak) keys, per-thread max
            double kmax = -1.0;
            #pragma unroll
            for (int j=0;j<4;++j){
                float dx=ptx[j]-lx, dy=pty[j]-ly, dz=ptz[j]-lz;
                float d = dx*dx + dy*dy + dz*dz;
                dst[j] = fminf(dst[j], d);
                // argmax key: larger dist wins, tie -> smaller index
                double kd = __hiloint2double((int)__float_as_uint(dst[j]),
                                             4095 - (tid + j*1024));
                kmax = fmax(kmax, kd);
            }
            // B: in-wave DPP reduce -> lane 63
            kmax = wavemax64(kmax);
            if ((tid&63)==63) warr[it&1][tid>>6] = kmax;
            __syncthreads();
            // C: all lanes read one of 16 wave entries, reduce in-register
            double g = warr[it&1][tid&15];
            g = rowmax16(g);
            int last = 4095 - (int)(u32)__double2loint(g);
            lx = px[last]; ly = py[last]; lz = pz[last];
            if (tid==0){
                idx2[b*WM+it] = last;
                int o3 = (b*WM+it)*3;
                out[O_P2A+o3]=lx; out[O_P2A+o3+1]=ly; out[O_P2A+o3+2]=lz;
                out[O_P2B+o3]=lx; out[O_P2B+o3+1]=ly; out[O_P2B+o3+2]=lz;
            }
        }
    } else {
        int wid = tid>>6, lane = tid&63;
        int grow = ((int)blockIdx.x-4)*16 + wid;   // global row, same batch across block
        int n = grow & 4095;
        float qx=px[n], qy=py[n], qz=pz[n];
        float qq = qx*qx+qy*qy+qz*qz;
        u64 lst[WKNN];
        #pragma unroll
        for (int j=0;j<WKNN;++j) lst[j]=~0ull;
        for (int t=0;t<64;++t){
            int c = lane + t*64;
            float sx=px[c], sy=py[c], sz=pz[c];
            float ss = sx*sx+sy*sy+sz*sz;
            float inner = qx*sx+qy*sy+qz*sz;
            float nd = (2.0f*inner - qq) - ss;   // reference formula order
            // maximize nd, tie -> smaller index  => ascending key
            u64 key = ((u64)(0xFFFFFFFFu - encf(nd))<<32) | (u32)c;
            ins<WKNN>(lst, key);
        }
        int ob = grow*WKNN;
        for (int r=0;r<WKNN;++r){
            u64 k = lst[0];
            #pragma unroll
            for (int m=32;m;m>>=1){ u64 o = shflx64(k,m); k = o<k?o:k; }
            if (lane==0) idx1[ob+r] = (int)(k & 0xFFFFFFFFu);
            if (lst[0]==k){
                #pragma unroll
                for (int j=0;j<WKNN-1;++j) lst[j]=lst[j+1];
                lst[WKNN-1]=~0ull;
            }
        }
    }
}

// ============================================================
// K2: edgeconv1 BN stats (sum, sumsq per 64 ch over B*N*K)
// ============================================================
__global__ __launch_bounds__(256,1)
void k2_ec1_stats(const float* __restrict__ x, const float* __restrict__ w1,
                  const int* __restrict__ idx1, float* __restrict__ acc){
    __shared__ float as[64], aq[64];
    int tid = threadIdx.x;
    if (tid < 64){ as[tid]=0.f; aq[tid]=0.f; }
    __syncthreads();
    int cg = tid & 7, sg = tid >> 3;
    int chb = cg*8;
    float w[8][6];
    #pragma unroll
    for (int i=0;i<8;++i){
        #pragma unroll
        for (int j=0;j<6;++j) w[i][j] = w1[(chb+i)*6+j];
    }
    float s[8]={0,0,0,0,0,0,0,0}, q[8]={0,0,0,0,0,0,0,0};
    int s0 = (int)blockIdx.x*1024 + sg*32;
    for (int i=0;i<32;++i){
        int smp = s0+i;
        int bn = smp/WKNN;
        int j = idx1[smp];
        int bb = bn >> 12;
        const float* ct = x + bn*3;
        const float* nb = x + (bb*WN + j)*3;
        float c0=ct[0],c1=ct[1],c2=ct[2];
        float f0=nb[0]-c0, f1=nb[1]-c1, f2=nb[2]-c2;
        #pragma unroll
        for (int c=0;c<8;++c){
            float y = w[c][0]*f0 + w[c][1]*f1 + w[c][2]*f2
                    + w[c][3]*c0 + w[c][4]*c1 + w[c][5]*c2;
            s[c] += y; q[c] = fmaf(y,y,q[c]);
        }
    }
    #pragma unroll
    for (int c=0;c<8;++c){ atomicAdd(&as[chb+c], s[c]); atomicAdd(&aq[chb+c], q[c]); }
    __syncthreads();
    if (tid < 64){ atomicAdd(&acc[tid], as[tid]); atomicAdd(&acc[64+tid], aq[tid]); }
}

// ============================================================
// K4: edgeconv1 apply (BN + leaky + max over k) -> x1 [B,N,64]
// ============================================================
__global__ __launch_bounds__(256,1)
void k4_ec1_apply(const float* __restrict__ x, const float* __restrict__ w1,
                  const float* __restrict__ g1, const float* __restrict__ b1,
                  const int* __restrict__ idx1, const float* __restrict__ acc,
                  float* __restrict__ x1){
    int lin = (int)blockIdx.x*256 + threadIdx.x;
    int row = lin >> 3, cg = lin & 7, chb = cg*8;
    int bb = row >> 12;
    const float Pinv = 1.0f/(float)(WB*WN*WKNN);
    float aa[8], cc[8], w[8][6];
    #pragma unroll
    for (int i=0;i<8;++i){
        int ch = chb+i;
        float mean = acc[ch]*Pinv;
        float var  = acc[64+ch]*Pinv - mean*mean;
        float rstd = rsqrtf(var + BEPS);
        aa[i] = g1[ch]*rstd;
        cc[i] = b1[ch] - mean*aa[i];
        #pragma unroll
        for (int j=0;j<6;++j) w[i][j]=w1[ch*6+j];
    }
    const float* ct = x + row*3;
    float c0=ct[0],c1=ct[1],c2=ct[2];
    float mx[8];
    #pragma unroll
    for (int i=0;i<8;++i) mx[i] = -1e30f;
    for (int k=0;k<WKNN;++k){
        int j = idx1[row*WKNN+k];
        const float* nb = x + (bb*WN + j)*3;
        float f0=nb[0]-c0, f1=nb[1]-c1, f2=nb[2]-c2;
        #pragma unroll
        for (int c=0;c<8;++c){
            float y = w[c][0]*f0 + w[c][1]*f1 + w[c][2]*f2
                    + w[c][3]*c0 + w[c][4]*c1 + w[c][5]*c2;
            float v = fmaf(y, aa[c], cc[c]);
            v = fmaxf(v, 0.2f*v);
            mx[c] = fmaxf(mx[c], v);
        }
    }
    #pragma unroll
    for (int c=0;c<8;++c) x1[row*64 + chb + c] = mx[c];
}

// ============================================================
// K5: xx1[row] = sum(x1[row]^2)
// ============================================================
__global__ __launch_bounds__(256,1)
void k5_xx1(const float* __restrict__ x1, float* __restrict__ xx1){
    int wid = threadIdx.x>>6, lane = threadIdx.x&63;
    int row = (int)blockIdx.x*4 + wid;
    float v = x1[row*64+lane];
    float s = v*v;
    #pragma unroll
    for (int m=32;m;m>>=1) s += __shfl_xor(s,m,64);
    if (lane==0) xx1[row]=s;
}

// ============================================================
// K6: knn-2 on x1 (C=64): fused 64x128x64 reg-tiled GEMM + top-20
// grid 256 (B x 64 q-tiles), 512 threads
// ============================================================
__global__ __launch_bounds__(512,1)
void k6_knn2(const float* __restrict__ x1, const float* __restrict__ xx1,
             int* __restrict__ idx2nn){
    __shared__ __align__(16) float Qt[64*64];
    __shared__ __align__(16) float St[128*68];
    __shared__ float Sxx[128];
    float* Dt = St;  // dist tile [64][132] overlays St (8448 <= 8704 floats)
    int tid = threadIdx.x, wid = tid>>6, lane = tid&63;
    int b = (int)blockIdx.x >> 6, qt = (int)blockIdx.x & 63;
    const float* xb = x1 + b*WN*64;
    for (int i=tid; i<64*16; i+=512){
        int r = i>>4, c4 = i&15;
        *(float4*)&Qt[r*64 + c4*4] = *(const float4*)&xb[(qt*64+r)*64 + c4*4];
    }
    float qxx[8];
    #pragma unroll
    for (int i=0;i<8;++i) qxx[i] = xx1[b*WN + qt*64 + wid*8 + i];
    u64 lst[WKNN];
    #pragma unroll
    for (int j=0;j<WKNN;++j) lst[j]=~0ull;
    int sq = tid>>3, seg = tid&7;
    for (int ct=0; ct<32; ++ct){
        int cb = ct*128;
        __syncthreads();   // protect St/Dt from previous iteration readers
        for (int i=tid; i<128*16; i+=512){
            int r=i>>4, c4=i&15;
            *(float4*)&St[r*68 + c4*4] = *(const float4*)&xb[(cb+r)*64 + c4*4];
        }
        if (tid < 128) Sxx[tid] = xx1[b*WN + cb + tid];
        __syncthreads();
        float acc[8][2];
        #pragma unroll
        for (int i=0;i<8;++i){ acc[i][0]=0.f; acc[i][1]=0.f; }
        #pragma unroll 4
        for (int d4=0; d4<16; ++d4){
            float4 s0 = *(const float4*)&St[lane*68 + d4*4];
            float4 s1 = *(const float4*)&St[(lane+64)*68 + d4*4];
            #pragma unroll
            for (int i=0;i<8;++i){
                float4 qv = *(const float4*)&Qt[(wid*8+i)*64 + d4*4];
                acc[i][0] += qv.x*s0.x + qv.y*s0.y + qv.z*s0.z + qv.w*s0.w;
                acc[i][1] += qv.x*s1.x + qv.y*s1.y + qv.z*s1.z + qv.w*s1.w;
            }
        }
        __syncthreads();   // all waves done reading St before Dt overwrite
        float sx0 = Sxx[lane], sx1 = Sxx[lane+64];
        #pragma unroll
        for (int i=0;i<8;++i){
            int r = wid*8+i;
            Dt[r*132 + lane]      = (2.0f*acc[i][0] - qxx[i]) - sx0;
            Dt[r*132 + lane + 64] = (2.0f*acc[i][1] - qxx[i]) - sx1;
        }
        __syncthreads();
        #pragma unroll
        for (int m=0;m<16;++m){
            int col = seg*16+m;
            float nd = Dt[sq*132 + col];
            u64 key = ((u64)(0xFFFFFFFFu - encf(nd))<<32) | (u32)(cb+col);
            ins<WKNN>(lst,key);
        }
    }
    // merge 8 seg-threads (consecutive, same wave) per query
    int ob = (b*WN + qt*64 + sq)*WKNN;
    for (int r=0;r<WKNN;++r){
        u64 k = lst[0];
        #pragma unroll
        for (int m=4;m;m>>=1){ u64 o=shflx64(k,m); k = o<k?o:k; }
        if ((tid&7)==0) idx2nn[ob+r] = (int)(k & 0xFFFFFFFFu);
        if (lst[0]==k){
            #pragma unroll
            for (int j=0;j<WKNN-1;++j) lst[j]=lst[j+1];
            lst[WKNN-1]=~0ull;
        }
    }
}

// ============================================================
// K7: edgeconv2 BN stats. grid 256 x 512 thr; wave=8ch, lane=row
// ============================================================
__global__ __launch_bounds__(512,1)
void k7_ec2_stats(const float* __restrict__ x1, const float* __restrict__ w2,
                  const int* __restrict__ idx2nn, float* __restrict__ acc){
    __shared__ __align__(16) float wsm[64*128];
    __shared__ float as[64], aq[64];
    int tid = threadIdx.x, wid = tid>>6, lane = tid&63;
    for (int i=tid; i<2048; i+=512)
        *(float4*)&wsm[i*4] = *(const float4*)&w2[i*4];
    if (tid<64){ as[tid]=0.f; aq[tid]=0.f; }
    __syncthreads();
    int row = (int)blockIdx.x*64 + lane;
    int b = row >> 12;
    const float* xr  = x1 + row*64;
    const float* xbb = x1 + b*WN*64;
    float ss[8]={0,0,0,0,0,0,0,0}, qs[8]={0,0,0,0,0,0,0,0};
    for (int kc=0; kc<5; ++kc){
        int jj[4];
        #pragma unroll
        for (int kk=0;kk<4;++kk) jj[kk] = idx2nn[row*WKNN + kc*4 + kk];
        float av[8][4];
        #pragma unroll
        for (int c=0;c<8;++c){ av[c][0]=0;av[c][1]=0;av[c][2]=0;av[c][3]=0; }
        #pragma unroll 4
        for (int dc=0; dc<16; ++dc){
            float4 cv = *(const float4*)&xr[dc*4];
            float4 fv[4];
            #pragma unroll
            for (int kk=0;kk<4;++kk){
                float4 nv = *(const float4*)&xbb[jj[kk]*64 + dc*4];
                fv[kk].x=nv.x-cv.x; fv[kk].y=nv.y-cv.y; fv[kk].z=nv.z-cv.z; fv[kk].w=nv.w-cv.w;
            }
            #pragma unroll
            for (int c=0;c<8;++c){
                float4 wv = *(const float4*)&wsm[(wid*8+c)*128 + dc*4];
                #pragma unroll
                for (int kk=0;kk<4;++kk)
                    av[c][kk] += wv.x*fv[kk].x + wv.y*fv[kk].y + wv.z*fv[kk].z + wv.w*fv[kk].w;
            }
        }
        #pragma unroll 4
        for (int dc=16; dc<32; ++dc){
            float4 cv = *(const float4*)&xr[(dc-16)*4];
            #pragma unroll
            for (int c=0;c<8;++c){
                float4 wv = *(const float4*)&wsm[(wid*8+c)*128 + dc*4];
                float dv = wv.x*cv.x + wv.y*cv.y + wv.z*cv.z + wv.w*cv.w;
                #pragma unroll
                for (int kk=0;kk<4;++kk) av[c][kk] += dv;
            }
        }
        #pragma unroll
        for (int c=0;c<8;++c){
            #pragma unroll
            for (int kk=0;kk<4;++kk){ ss[c]+=av[c][kk]; qs[c]=fmaf(av[c][kk],av[c][kk],qs[c]); }
        }
    }
    #pragma unroll
    for (int c=0;c<8;++c){ atomicAdd(&as[wid*8+c], ss[c]); atomicAdd(&aq[wid*8+c], qs[c]); }
    __syncthreads();
    if (tid<64){ atomicAdd(&acc[128+tid], as[tid]); atomicAdd(&acc[192+tid], aq[tid]); }
}

// ============================================================
// K9: edgeconv2 apply -> x2 [B,N,64]
// ============================================================
__global__ __launch_bounds__(512,1)
void k9_ec2_apply(const float* __restrict__ x1, const float* __restrict__ w2,
                  const float* __restrict__ g2, const float* __restrict__ b2,
                  const int* __restrict__ idx2nn, const float* __restrict__ acc,
                  float* __restrict__ x2){
    __shared__ __align__(16) float wsm[64*128];
    int tid = threadIdx.x, wid = tid>>6, lane = tid&63;
    for (int i=tid; i<2048; i+=512)
        *(float4*)&wsm[i*4] = *(const float4*)&w2[i*4];
    __syncthreads();
    const float Pinv = 1.0f/(float)(WB*WN*WKNN);
    float aa[8], cc[8];
    #pragma unroll
    for (int c=0;c<8;++c){
        int ch = wid*8+c;
        float mean = acc[128+ch]*Pinv;
        float var  = acc[192+ch]*Pinv - mean*mean;
        float rstd = rsqrtf(var + BEPS);
        aa[c] = g2[ch]*rstd;
        cc[c] = b2[ch] - mean*aa[c];
    }
    int row = (int)blockIdx.x*64 + lane;
    int b = row>>12;
    const float* xr  = x1 + row*64;
    const float* xbb = x1 + b*WN*64;
    float mx[8];
    #pragma unroll
    for (int c=0;c<8;++c) mx[c] = -1e30f;
    for (int kc=0;kc<5;++kc){
        int jj[4];
        #pragma unroll
        for (int kk=0;kk<4;++kk) jj[kk]=idx2nn[row*WKNN+kc*4+kk];
        float av[8][4];
        #pragma unroll
        for (int c=0;c<8;++c){ av[c][0]=0;av[c][1]=0;av[c][2]=0;av[c][3]=0; }
        #pragma unroll 4
        for (int dc=0;dc<16;++dc){
            float4 cv = *(const float4*)&xr[dc*4];
            float4 fv[4];
            #pragma unroll
            for (int kk=0;kk<4;++kk){
                float4 nv = *(const float4*)&xbb[jj[kk]*64 + dc*4];
                fv[kk].x=nv.x-cv.x; fv[kk].y=nv.y-cv.y; fv[kk].z=nv.z-cv.z; fv[kk].w=nv.w-cv.w;
            }
            #pragma unroll
            for (int c=0;c<8;++c){
                float4 wv = *(const float4*)&wsm[(wid*8+c)*128 + dc*4];
                #pragma unroll
                for (int kk=0;kk<4;++kk)
                    av[c][kk] += wv.x*fv[kk].x + wv.y*fv[kk].y + wv.z*fv[kk].z + wv.w*fv[kk].w;
            }
        }
        #pragma unroll 4
        for (int dc=16;dc<32;++dc){
            float4 cv = *(const float4*)&xr[(dc-16)*4];
            #pragma unroll
            for (int c=0;c<8;++c){
                float4 wv = *(const float4*)&wsm[(wid*8+c)*128 + dc*4];
                float dv = wv.x*cv.x + wv.y*cv.y + wv.z*cv.z + wv.w*cv.w;
                #pragma unroll
                for (int kk=0;kk<4;++kk) av[c][kk] += dv;
            }
        }
        #pragma unroll
        for (int c=0;c<8;++c){
            #pragma unroll
            for (int kk=0;kk<4;++kk){
                float v = fmaf(av[c][kk], aa[c], cc[c]);
                v = fmaxf(v, 0.2f*v);
                mx[c] = fmaxf(mx[c], v);
            }
        }
    }
    #pragma unroll
    for (int c=0;c<8;++c) x2[row*64 + wid*8 + c] = mx[c];
}

// ============================================================
// K10: out-knn (top-8 of p2 vs x), agg = mean of x2 rows,
//      pre-BN Yf/Yc written TRANSPOSED directly into out,
//      accumulate BN stats.
// grid 256 (16 queries each), 256 thr (wave/query x4 sequential)
// ============================================================
__global__ __launch_bounds__(256,1)
void k10_out(const float* __restrict__ x, const float* __restrict__ x2,
             const int* __restrict__ idx2, const float* __restrict__ wf,
             const float* __restrict__ wc, float* __restrict__ out,
             float* __restrict__ acc){
    __shared__ float px[WN], py[WN], pz[WN];
    __shared__ __align__(16) float aggs[4][64];
    __shared__ float sacc[1024];
    int tid=threadIdx.x, wid=tid>>6, lane=tid&63;
    int b = (int)blockIdx.x >> 6;
    int mb = ((int)blockIdx.x & 63)*16;
    const float* xb = x + b*WN*3;
    for (int i=tid;i<WN*3;i+=256){
        float v=xb[i]; int n=i/3,c=i-n*3;
        if(c==0)px[n]=v; else if(c==1)py[n]=v; else pz[n]=v;
    }
    for (int i=tid;i<1024;i+=256) sacc[i]=0.f;
    __syncthreads();
    for (int qq=0;qq<4;++qq){
        int m = mb + wid*4 + qq;
        int pi = idx2[b*WM+m];
        float qx=px[pi], qy=py[pi], qz=pz[pi];
        u64 lst[WOUTK];
        #pragma unroll
        for (int j=0;j<WOUTK;++j) lst[j]=~0ull;
        for (int t=0;t<64;++t){
            int c = lane + t*64;
            float dx=qx-px[c], dy=qy-py[c], dz=qz-pz[c];
            float d = dx*dx+dy*dy+dz*dz;
            u64 key = ((u64)encf(d)<<32) | (u32)c;   // min d, tie -> min idx
            ins<WOUTK>(lst,key);
        }
        int jr[WOUTK];
        #pragma unroll
        for (int r=0;r<WOUTK;++r){
            u64 k=lst[0];
            #pragma unroll
            for (int mm=32;mm;mm>>=1){ u64 o=shflx64(k,mm); k = o<k?o:k; }
            jr[r] = (int)(k&0xFFFFFFFFu);
            if (lst[0]==k){
                #pragma unroll
                for (int j=0;j<WOUTK-1;++j) lst[j]=lst[j+1];
                lst[WOUTK-1]=~0ull;
            }
        }
        float a = 0.f;
        #pragma unroll
        for (int r=0;r<WOUTK;++r) a += x2[(b*WN + jr[r])*64 + lane];
        a *= 0.125f;
        aggs[wid][lane] = a;
        __syncthreads();
        #pragma unroll
        for (int i=0;i<4;++i){
            int o = lane + 64*i;
            const float4* wfp = (const float4*)(wf + o*64);
            const float4* wcp = (const float4*)(wc + o*64);
            float af=0.f, ac=0.f;
            #pragma unroll
            for (int d4=0;d4<16;++d4){
                float4 avv = *(const float4*)&aggs[wid][d4*4];
                float4 w1v = wfp[d4];
                float4 w2v = wcp[d4];
                af += w1v.x*avv.x + w1v.y*avv.y + w1v.z*avv.z + w1v.w*avv.w;
                ac += w2v.x*avv.x + w2v.y*avv.y + w2v.z*avv.z + w2v.w*avv.w;
            }
            // pre-BN values straight to final transposed slot [b, o, m]
            out[O_F + (b*WOD + o)*WM + m] = af;
            out[O_C + (b*WOD + o)*WM + m] = ac;
            atomicAdd(&sacc[o],       af);
            atomicAdd(&sacc[256+o],   af*af);
            atomicAdd(&sacc[512+o],   ac);
            atomicAdd(&sacc[768+o],   ac*ac);
        }
        __syncthreads();
    }
    for (int i=tid;i<1024;i+=256) atomicAdd(&acc[256+i], sacc[i]);
}

// ============================================================
// K12: in-place BN-normalize the f/c halves of out (coalesced)
// ============================================================
__global__ __launch_bounds__(256,1)
void k12_final(const float* __restrict__ acc,
               const float* __restrict__ gf, const float* __restrict__ bf,
               const float* __restrict__ gc, const float* __restrict__ bc,
               float* __restrict__ out){
    int t = (int)blockIdx.x*256 + threadIdx.x;   // 0 .. 2*2^20
    int half = t >> 20;
    int r = t & 0xFFFFF;
    int o = (r >> 10) & 255;
    const float Pinv = 1.0f/4096.0f;
    float sum = acc[(half?768:256) + o];
    float sq  = acc[(half?1024:512) + o];
    float mean = sum*Pinv;
    float var  = sq*Pinv - mean*mean;
    float rstd = rsqrtf(var + BEPS);
    float g  = half ? gc[o] : gf[o];
    float bb = half ? bc[o] : bf[o];
    float y = out[t];
    out[t] = (y-mean)*rstd*g + bb;
}

extern "C" void kernel_launch(void* const* d_in, const int* in_sizes, int n_in,
                              void* d_out, int out_size, void* d_ws, size_t ws_size,
                              hipStream_t stream){
    const float* x  = (const float*)d_in[0];
    const float* w1 = (const float*)d_in[1];
    const float* g1 = (const float*)d_in[2];
    const float* b1 = (const float*)d_in[3];
    const float* w2 = (const float*)d_in[4];
    const float* g2 = (const float*)d_in[5];
    const float* b2 = (const float*)d_in[6];
    const float* wf = (const float*)d_in[7];
    const float* gf = (const float*)d_in[8];
    const float* bf = (const float*)d_in[9];
    const float* wc = (const float*)d_in[10];
    const float* gc = (const float*)d_in[11];
    const float* bc = (const float*)d_in[12];
    float* out = (float*)d_out;
    float* wsf = (float*)d_ws;
    int*   wsi = (int*)d_ws;
    float* ACC    = wsf + ACC_F;
    int*   idx1   = wsi + IDX1_I;
    int*   idx2nn = wsi + IDX2NN_I;
    int*   idx2   = wsi + IDX2_I;
    float* x1     = wsf + X1_F;
    float* xx1    = wsf + XX1_F;
    float* x2     = wsf + X2_F;

    hipMemsetAsync(ACC, 0, 1280*sizeof(float), stream);
    k1_fps_knn1 <<<1028,1024,0,stream>>>(x,out,idx1,idx2);
    k2_ec1_stats<<<320, 256, 0,stream>>>(x,w1,idx1,ACC);
    k4_ec1_apply<<<512, 256, 0,stream>>>(x,w1,g1,b1,idx1,ACC,x1);
    k5_xx1      <<<4096,256, 0,stream>>>(x1,xx1);
    k6_knn2     <<<256, 512, 0,stream>>>(x1,xx1,idx2nn);
    k7_ec2_stats<<<256, 512, 0,stream>>>(x1,w2,idx2nn,ACC);
    k9_ec2_apply<<<256, 512, 0,stream>>>(x1,w2,g2,b2,idx2nn,ACC,x2);
    k10_out     <<<256, 256, 0,stream>>>(x,x2,idx2,wf,wc,out,ACC);
    k12_final   <<<8192,256, 0,stream>>>(ACC,gf,bf,gc,bc,out);
}